// Round 4
// baseline (216.264 us; speedup 1.0000x reference)
//
#include <hip/hip_runtime.h>

// Geometry: B=4, C=96 (F=32 lights x 3), H=W=256. NCHW fp32.
// img/light element (b,c,h,w) at ((b*96+c)*65536 + h*256 + w). Out (4,3,256,256).
//
// R2/R3 design: block = 4 waves x 64 lanes. All waves cover the SAME 64
// float4-quads (lane = quad), so every global load is one fully-contiguous 1KB
// wave transaction inside a single channel plane. Wave w accumulates lights
// [8w, 8w+8). Partials (9 sums x 4 pixels per lane) reduced across waves via
// padded LDS; wave 0 does the 3x3 solve + store. XCD-bijective swizzle gives
// each XCD a contiguous p-range.

constexpr int QROW = 16384;   // float4 quads per channel plane (65536 px / 4)

__device__ __forceinline__ float fc(const float4 v, int j) {
    return j == 0 ? v.x : j == 1 ? v.y : j == 2 ? v.z : v.w;
}
__device__ __forceinline__ void setc(float4& v, int j, float x) {
    if (j == 0) v.x = x; else if (j == 1) v.y = x; else if (j == 2) v.z = x; else v.w = x;
}

__global__ __launch_bounds__(256, 4) void LS_44160853737780_kernel(
    const float4* __restrict__ img,
    const float4* __restrict__ light,
    float4* __restrict__ out)
{
    // [waves 1..3][lane][9 accums x 4 px], padded 36->37 floats (stride coprime w/ 32)
    __shared__ float red[3][64][37];

    int blk  = blockIdx.x;                      // 0..1023
    int swz  = (blk & 7) * 128 + (blk >> 3);    // XCD k owns contiguous swz range
    int b    = swz >> 8;                        // batch (256 blocks per batch)
    int p0   = (swz & 255) * 64;                // first quad of this block
    int lane = threadIdx.x & 63;
    int w    = threadIdx.x >> 6;                // wave id 0..3 -> lights 8w..8w+7
    int p    = p0 + lane;

    const float4* ib = img   + (size_t)(b * 96 + w * 24) * QROW + p;
    const float4* lb = light + (size_t)(b * 96 + w * 24) * QROW + p;

    float A00[4] = {0,0,0,0}, A01[4] = {0,0,0,0}, A02[4] = {0,0,0,0},
          A11[4] = {0,0,0,0}, A12[4] = {0,0,0,0}, A22[4] = {0,0,0,0},
          r0[4]  = {0,0,0,0}, r1[4]  = {0,0,0,0}, r2[4]  = {0,0,0,0};

    #pragma unroll
    for (int f = 0; f < 8; ++f) {
        float4 ix = ib[(3*f+0)*QROW];
        float4 iy = ib[(3*f+1)*QROW];
        float4 iz = ib[(3*f+2)*QROW];
        float4 lx = lb[(3*f+0)*QROW];
        float4 ly = lb[(3*f+1)*QROW];
        float4 lz = lb[(3*f+2)*QROW];
        #pragma unroll
        for (int j = 0; j < 4; ++j) {
            float x = fc(ix,j), y = fc(iy,j), z = fc(iz,j);
            float I = sqrtf(x*x + y*y + z*z);
            float a = fc(lx,j), c = fc(ly,j), d = fc(lz,j);
            A00[j] += a*a; A01[j] += a*c; A02[j] += a*d;
            A11[j] += c*c; A12[j] += c*d; A22[j] += d*d;
            r0[j]  += a*I; r1[j]  += c*I; r2[j]  += d*I;
        }
    }

    // Stash partials from waves 1..3; wave 0 accumulates.
    if (w > 0) {
        float* dst = red[w - 1][lane];
        #pragma unroll
        for (int j = 0; j < 4; ++j) {
            dst[0*4+j] = A00[j]; dst[1*4+j] = A01[j]; dst[2*4+j] = A02[j];
            dst[3*4+j] = A11[j]; dst[4*4+j] = A12[j]; dst[5*4+j] = A22[j];
            dst[6*4+j] = r0[j];  dst[7*4+j] = r1[j];  dst[8*4+j] = r2[j];
        }
    }
    __syncthreads();
    if (w != 0) return;

    #pragma unroll
    for (int s = 0; s < 3; ++s) {
        const float* src = red[s][lane];
        #pragma unroll
        for (int j = 0; j < 4; ++j) {
            A00[j] += src[0*4+j]; A01[j] += src[1*4+j]; A02[j] += src[2*4+j];
            A11[j] += src[3*4+j]; A12[j] += src[4*4+j]; A22[j] += src[5*4+j];
            r0[j]  += src[6*4+j]; r1[j]  += src[7*4+j]; r2[j]  += src[8*4+j];
        }
    }

    float4 o0, o1, o2;
    #pragma unroll
    for (int j = 0; j < 4; ++j) {
        float a00 = A00[j], a01 = A01[j], a02 = A02[j],
              a11 = A11[j], a12 = A12[j], a22 = A22[j];
        float c00 = a11*a22 - a12*a12;
        float c01 = a02*a12 - a01*a22;
        float c02 = a01*a12 - a02*a11;
        float c11 = a00*a22 - a02*a02;
        float c12 = a01*a02 - a00*a12;
        float c22 = a00*a11 - a01*a01;
        float det = a00*c00 + a01*c01 + a02*c02;
        float inv = 1.0f / det;
        float n0 = (c00*r0[j] + c01*r1[j] + c02*r2[j]) * inv;
        float n1 = (c01*r0[j] + c11*r1[j] + c12*r2[j]) * inv;
        float n2 = (c02*r0[j] + c12*r1[j] + c22*r2[j]) * inv;
        float nn = sqrtf(n0*n0 + n1*n1 + n2*n2);
        float s  = 1.0f / (nn + 1e-10f);
        setc(o0, j, n0*s);
        setc(o1, j, n1*s);
        setc(o2, j, n2*s);
    }

    float4* ob = out + (size_t)(b * 3) * QROW + p;
    ob[0]        = o0;
    ob[QROW]     = o1;
    ob[2 * QROW] = o2;
}

extern "C" void kernel_launch(void* const* d_in, const int* in_sizes, int n_in,
                              void* d_out, int out_size, void* d_ws, size_t ws_size,
                              hipStream_t stream) {
    (void)in_sizes; (void)n_in; (void)out_size; (void)d_ws; (void)ws_size;
    const float4* img   = (const float4*)d_in[0];
    const float4* light = (const float4*)d_in[1];
    float4* out = (float4*)d_out;
    // 65536 quads / 64 per block = 1024 blocks of 256 threads.
    LS_44160853737780_kernel<<<dim3(1024), dim3(256), 0, stream>>>(img, light, out);
}